// Round 10
// baseline (207.851 us; speedup 1.0000x reference)
//
#include <hip/hip_runtime.h>
#include <hip/hip_bf16.h>
#include <math.h>

#define BT   8192   // B*T
#define DD   256    // D
#define EE   16     // E
#define NN   8192   // N codebook entries (C == 1)

typedef __attribute__((ext_vector_type(8))) short short8;   // bf16x8 MFMA frag
typedef __attribute__((ext_vector_type(4))) float f32x4;    // MFMA accumulator

__device__ __forceinline__ unsigned short f2bf(float x) {
  union { float f; unsigned int u; } c; c.f = x;
  unsigned int r = (c.u + 0x7FFFu + ((c.u >> 16) & 1u)) >> 16;   // RNE
  return (unsigned short)r;
}
__device__ __forceinline__ unsigned int ordf(float d) {
  union { float f; unsigned int u; } c; c.f = d;
  return ((int)c.u < 0) ? ~c.u : (c.u | 0x80000000u);
}
__device__ __forceinline__ unsigned long long shflxor64(unsigned long long v, int m) {
  unsigned int lo = (unsigned int)v, hi = (unsigned int)(v >> 32);
  lo = __shfl_xor((int)lo, m);
  hi = __shfl_xor((int)hi, m);
  return ((unsigned long long)hi << 32) | lo;
}
__device__ __forceinline__ void gload_lds16(const void* g, void* l) {
  __builtin_amdgcn_global_load_lds((const __attribute__((address_space(1))) void*)g,
                                   (__attribute__((address_space(3))) void*)l, 16, 0, 0);
}

// ---------------- k_pre: fused Wt-transpose + embT + LN/proj/xmb ------------
// blocks [0,512):    W[d][n] fp32 -> Wt[n][d] bf16 (LDS-tiled, coalesced writes)
// blocks [512,544):  emb -> embT bf16 + sqe(half) + keys init
// blocks [544,800):  xmb bf16 cast, LayerNorm, projb bf16, sumexp zero
// v7-kept: LN/proj section stages P/gamma/beta in LDS.
#define XT_LD 65   // float4 row stride (64 + 1 pad -> conflict-free)
__global__ __launch_bounds__(256) void k_pre(const float* __restrict__ xs,
                                             const int* __restrict__ mm,
                                             const float* __restrict__ memb,
                                             const float* __restrict__ gamma,
                                             const float* __restrict__ beta,
                                             const float* __restrict__ P,
                                             const float* __restrict__ W,
                                             const float* __restrict__ emb,
                                             unsigned short* __restrict__ xmb,
                                             unsigned short* __restrict__ projb,
                                             unsigned short* __restrict__ Wt,
                                             unsigned short* __restrict__ embT,
                                             float* __restrict__ sqe,
                                             unsigned long long* __restrict__ keys,
                                             float* __restrict__ sumexp) {
  __shared__ __align__(16) float xt[32 * XT_LD * 4];   // 33 KB shared scratch
  __shared__ float stats[32][2];
  __shared__ __align__(16) float Pl[DD * EE];          // 16 KB (LN blocks)
  __shared__ __align__(16) float gl[DD], bl[DD];       //  2 KB
  int bid = blockIdx.x;
  int tid = threadIdx.x;

  if (bid < 512) {             // ---- Wt transpose: 64n x 64d tile ----
    int n0 = (bid & 127) * 64;
    int d0 = (bid >> 7) * 64;
    #pragma unroll
    for (int pass = 0; pass < 16; pass++) {
      int idx = pass * 256 + tid;
      int dd = idx >> 6, ln = idx & 63;
      xt[ln * 65 + dd] = W[(size_t)(d0 + dd) * NN + n0 + ln];
    }
    __syncthreads();
    #pragma unroll
    for (int pass = 0; pass < 2; pass++) {
      int g = pass * 256 + tid;
      int row = g >> 3, c8 = g & 7;
      short8 v;
      #pragma unroll
      for (int i = 0; i < 8; i++) v[i] = (short)f2bf(xt[row * 65 + c8 * 8 + i]);
      *(short8*)(Wt + (size_t)(n0 + row) * DD + d0 + c8 * 8) = v;
    }
    return;
  }
  if (bid < 544) {             // ---- embT + sqe(half) + keys ----
    int n = (bid - 512) * 256 + tid;
    float e[EE];
    float sq = 0.f;
    #pragma unroll
    for (int k = 0; k < EE; k++) { e[k] = emb[k * NN + n]; sq += e[k] * e[k]; }
    short8 lo, hi;
    #pragma unroll
    for (int k = 0; k < 8; k++) { lo[k] = (short)f2bf(e[k]); hi[k] = (short)f2bf(e[k + 8]); }
    *(short8*)(embT + (size_t)n * EE)     = lo;
    *(short8*)(embT + (size_t)n * EE + 8) = hi;
    sqe[n] = 0.5f * sq;        // pre-halved: argmin(0.5|e|^2 - p.e) == argmin dist
    keys[n] = ~0ULL;
    return;
  }
  // ---- LN + projection + xmb ----
  int pb = bid - 544;
  int t0 = pb * 32;
  int w = tid >> 6;
  int col4 = tid & 63;
  float4 mb4 = ((const float4*)memb)[col4];

  // stage P/gamma/beta to LDS (completes by the first __syncthreads)
  #pragma unroll
  for (int i = tid; i < DD * EE / 4; i += 256)
    ((float4*)Pl)[i] = ((const float4*)P)[i];
  if (tid < DD / 4) {
    ((float4*)gl)[tid] = ((const float4*)gamma)[tid];
    ((float4*)bl)[tid] = ((const float4*)beta)[tid];
  }

  #pragma unroll
  for (int j = 0; j < 8; j++) {
    int k = tid + j * 256;
    int row = w + j * 4;
    float4 xv = ((const float4*)xs)[(size_t)pb * 2048 + k];
    int m = mm[t0 + row];
    float4 v = m ? mb4 : xv;
    ushort2 o01 = { f2bf(v.x), f2bf(v.y) };
    ushort2 o23 = { f2bf(v.z), f2bf(v.w) };
    ((ushort2*)(xmb + (size_t)(t0 + row) * DD + col4 * 4))[0] = o01;
    ((ushort2*)(xmb + (size_t)(t0 + row) * DD + col4 * 4))[1] = o23;
    *(float4*)&xt[(row * XT_LD + col4) * 4] = xv;
  }
  __syncthreads();
  {
    int t = tid >> 3, g = tid & 7;
    float s = 0.f, s2 = 0.f;
    #pragma unroll
    for (int i = 0; i < 8; i++) {
      float4 v = *(const float4*)&xt[(t * XT_LD + g * 8 + i) * 4];
      s  += v.x + v.y + v.z + v.w;
      s2 += v.x * v.x + v.y * v.y + v.z * v.z + v.w * v.w;
    }
    #pragma unroll
    for (int m = 1; m <= 4; m <<= 1) { s += __shfl_xor(s, m); s2 += __shfl_xor(s2, m); }
    if (g == 0) {
      float mu = s * (1.0f / DD);
      float var = s2 * (1.0f / DD) - mu * mu;
      stats[t][0] = mu;
      stats[t][1] = rsqrtf(var + 1e-5f);
    }
  }
  if (tid < 32) sumexp[t0 + tid] = 0.f;
  __syncthreads();
  {
    int t = tid >> 3, e0 = (tid & 7) * 2;
    float mu = stats[t][0], rstd = stats[t][1];
    float a0 = 0.f, a1 = 0.f;
    for (int d = 0; d < DD; d += 4) {
      float4 xv = *(const float4*)&xt[(t * XT_LD + (d >> 2)) * 4];
      float xd[4] = { xv.x, xv.y, xv.z, xv.w };
      #pragma unroll
      for (int dd = 0; dd < 4; dd++) {
        float h = (xd[dd] - mu) * rstd * gl[d + dd] + bl[d + dd];
        a0 += h * Pl[(d + dd) * EE + e0];
        a1 += h * Pl[(d + dd) * EE + e0 + 1];
      }
    }
    ushort2 o = { f2bf(a0), f2bf(a1) };
    *(ushort2*)(projb + (size_t)(t0 + t) * EE + e0) = o;
  }
}

// ------- k_argmin: MFMA dist + 32-bit (ord,idx) argmin ----------------------
// v7-kept: sqe pre-halved; 32-bit best-ord/best-idx in the hot loop; first-
// occurrence tie semantics preserved.
#define NS4 8
#define ASEG (NN / NS4)   // 1024 n per block
__global__ __launch_bounds__(256) void k_argmin(const unsigned short* __restrict__ projb,
                                                const unsigned short* __restrict__ embT,
                                                const float* __restrict__ sqe,
                                                unsigned long long* __restrict__ keys) {
  int tid = threadIdx.x;
  int w = tid >> 6, lane = tid & 63;
  int q = lane >> 4, c = lane & 15;
  int tw = blockIdx.x * 64 + w * 16;
  int nseg = blockIdx.y * ASEG;

  short8 a = {0, 0, 0, 0, 0, 0, 0, 0};
  if (q < 2) a = *(const short8*)(projb + (size_t)(tw + c) * EE + q * 8);

  unsigned int bo[4], bi[4];
  #pragma unroll
  for (int r = 0; r < 4; r++) { bo[r] = 0xFFFFFFFFu; bi[r] = 0u; }

  #pragma unroll 2
  for (int it = 0; it < ASEG / 16; it++) {
    int n = nseg + it * 16 + c;
    short8 b = {0, 0, 0, 0, 0, 0, 0, 0};
    if (q < 2) b = *(const short8*)(embT + (size_t)n * EE + q * 8);
    float sqh = sqe[n];
    f32x4 acc = (f32x4){0.f, 0.f, 0.f, 0.f};
    acc = __builtin_amdgcn_mfma_f32_16x16x32_bf16(a, b, acc, 0, 0, 0);
    #pragma unroll
    for (int r = 0; r < 4; r++) {
      float dist = sqh - acc[r];
      unsigned int u = ordf(dist);
      if (u < bo[r]) { bo[r] = u; bi[r] = (unsigned int)n; }
    }
  }
  unsigned long long bk[4];
  #pragma unroll
  for (int r = 0; r < 4; r++)
    bk[r] = ((unsigned long long)bo[r] << 32) | bi[r];
  #pragma unroll
  for (int r = 0; r < 4; r++) {
    #pragma unroll
    for (int m = 1; m <= 8; m <<= 1) {
      unsigned long long o = shflxor64(bk[r], m);
      bk[r] = o < bk[r] ? o : bk[r];
    }
  }
  if (c == 0) {
    #pragma unroll
    for (int r = 0; r < 4; r++)
      atomicMin(&keys[tw + q * 4 + r], bk[r]);
  }
}

// ------- k_ce5 v10: SINGLE-STAGE full-K 128x128 MFMA GEMM -------------------
// Short-K insight: K=256 means a 128x128 output tile's ENTIRE A+B panels fit
// LDS (64KB + 64KB = 128KB <= 160KB). So stage once (16 gload_lds/thread,
// all in flight together -> latency amortized), ONE vmcnt(0) + ONE barrier,
// then all 64 MFMAs/wave run with ZERO further synchronization. This deletes
// the per-K-step barrier+vmcnt overhead that m233 measured at ~72% of a
// 2-phase loop's wall — v5 paid it 8x per block; v9's big-tile alternative
// died of register pressure (252 combined regs, 2 waves/SIMD, MfmaUtil 15%).
// Cost: 128KB LDS -> 1 block/CU (8 waves, 2/SIMD). That cap makes register
// pressure FREE below spill, so the compiler can hoist ds_reads across the
// whole barrier-less K range (its lgkmcnt scheduling is the good part;
// barriers were what defeated it).
// Wave geometry = v5 (proven regs): 8 waves of 32x64, acc[2][4] = 32 regs.
// Bank swizzle (rule #21 both-sides involution): [row][k] rows are 512B
// (bank-aligned) -> store k-chunk ck at slot (ck&24)|((ck&7)^(row&7)),
// pre-swizzling the gload SOURCE (LDS dest lane-linear); ds_read applies
// the same XOR. Residual conflict: rows r, r+8 share slot offset, differ by
// 4KB -> same banks -> 2-way = free (m136).
__global__ __launch_bounds__(512, 2) void k_ce5(const unsigned short* __restrict__ xmb,
                                                const unsigned short* __restrict__ Wt,
                                                const unsigned long long* __restrict__ keys,
                                                float* __restrict__ sumexp,
                                                float* __restrict__ ltar) {
  __shared__ __align__(16) unsigned short ldsA[128 * 256];   // 64 KB
  __shared__ __align__(16) unsigned short ldsB[128 * 256];   // 64 KB
  int tid = threadIdx.x;
  int lane = tid & 63;
  int w = tid >> 6;
  int q = lane >> 4, c = lane & 15;
  int wm = w >> 1, wn = w & 1;
  int t0 = blockIdx.x * 128;
  int n0 = blockIdx.y * 128;

  f32x4 acc[2][4];
  #pragma unroll
  for (int mi = 0; mi < 2; mi++)
    #pragma unroll
    for (int ni = 0; ni < 4; ni++) acc[mi][ni] = (f32x4){0.f, 0.f, 0.f, 0.f};

  // ---- single stage: 4096 16B-slots per operand; 8 A + 8 B per thread ----
  // slot g = (row, s): row = g>>5, s = g&31; holds global chunk
  // ck = (s&24) | ((s&7) ^ (row&7)).  LDS dest lane-linear (gload_lds req).
  #pragma unroll
  for (int j = 0; j < 8; j++) {
    int g = j * 512 + tid;
    int row = g >> 5, s = g & 31;
    int ck = (s & 24) | ((s & 7) ^ (row & 7));
    gload_lds16(xmb + (size_t)(t0 + row) * DD + ck * 8, ldsA + g * 8);
    gload_lds16(Wt + (size_t)(n0 + row) * DD + ck * 8, ldsB + g * 8);
  }
  asm volatile("s_waitcnt vmcnt(0)" ::: "memory");
  __builtin_amdgcn_s_barrier();
  // ---- the ONLY barrier in the kernel; all compute below is sync-free ----

  #pragma unroll
  for (int kk = 0; kk < 8; kk++) {
    short8 a[2];
    #pragma unroll
    for (int mi = 0; mi < 2; mi++) {
      int row = wm * 32 + mi * 16 + c;
      int ck = kk * 4 + q;
      int s = (ck & 24) | ((ck & 7) ^ (row & 7));
      a[mi] = *(const short8*)(ldsA + row * 256 + s * 8);
    }
    #pragma unroll
    for (int ni = 0; ni < 4; ni++) {
      int col = wn * 64 + ni * 16 + c;
      int ck = kk * 4 + q;
      int s = (ck & 24) | ((ck & 7) ^ (col & 7));
      short8 b = *(const short8*)(ldsB + col * 256 + s * 8);
      #pragma unroll
      for (int mi = 0; mi < 2; mi++)
        acc[mi][ni] = __builtin_amdgcn_mfma_f32_16x16x32_bf16(a[mi], b, acc[mi][ni], 0, 0, 0);
    }
  }

  // epilogue: exp-sum per row + target-logit capture (unique writer grid-wide)
  int tg[2][4];
  #pragma unroll
  for (int mi = 0; mi < 2; mi++)
    #pragma unroll
    for (int r = 0; r < 4; r++)
      tg[mi][r] = (int)(unsigned int)(keys[t0 + wm * 32 + mi * 16 + q * 4 + r] & 0xFFFFFFFFULL);

  float rs[2][4];
  #pragma unroll
  for (int mi = 0; mi < 2; mi++)
    #pragma unroll
    for (int r = 0; r < 4; r++) rs[mi][r] = 0.f;

  #pragma unroll
  for (int mi = 0; mi < 2; mi++)
    #pragma unroll
    for (int ni = 0; ni < 4; ni++) {
      int col = n0 + wn * 64 + ni * 16 + c;
      #pragma unroll
      for (int r = 0; r < 4; r++) {
        float v = acc[mi][ni][r];
        if (col == tg[mi][r])
          ltar[t0 + wm * 32 + mi * 16 + q * 4 + r] = v;
        rs[mi][r] += __expf(v);
      }
    }

  #pragma unroll
  for (int mi = 0; mi < 2; mi++)
    #pragma unroll
    for (int r = 0; r < 4; r++) {
      float s = rs[mi][r];
      s += __shfl_xor(s, 1);
      s += __shfl_xor(s, 2);
      s += __shfl_xor(s, 4);
      s += __shfl_xor(s, 8);
      if (c == 0)
        atomicAdd(&sumexp[t0 + wm * 32 + mi * 16 + q * 4 + r], s);
    }
}

// ------- final: CE, masked mean ---------------------------------------------
__global__ __launch_bounds__(1024) void k_final(const float* __restrict__ sumexp,
                                                const float* __restrict__ ltar,
                                                const int* __restrict__ padm,
                                                const int* __restrict__ mm,
                                                float* __restrict__ out) {
  int tid = threadIdx.x;
  float sum = 0.f, cnt = 0.f;
  for (int t = tid; t < BT; t += 1024) {
    float ce = __logf(sumexp[t]) - ltar[t];
    if (padm[t] && mm[t]) { sum += ce; cnt += 1.f; }
  }
  #pragma unroll
  for (int off = 32; off; off >>= 1) { sum += __shfl_down(sum, off); cnt += __shfl_down(cnt, off); }
  __shared__ float rs[16], rc[16];
  int wid = tid >> 6, lane = tid & 63;
  if (lane == 0) { rs[wid] = sum; rc[wid] = cnt; }
  __syncthreads();
  if (tid == 0) {
    float S = 0.f, Cn = 0.f;
    for (int i = 0; i < 16; i++) { S += rs[i]; Cn += rc[i]; }
    out[0] = S / Cn;
  }
}

extern "C" void kernel_launch(void* const* d_in, const int* in_sizes, int n_in,
                              void* d_out, int out_size, void* d_ws, size_t ws_size,
                              hipStream_t stream) {
  const float* xs    = (const float*)d_in[0];
  const int*   padm  = (const int*)d_in[1];
  const int*   mm    = (const int*)d_in[2];
  const float* gamma = (const float*)d_in[3];
  const float* beta  = (const float*)d_in[4];
  const float* P     = (const float*)d_in[5];
  const float* emb   = (const float*)d_in[6];
  const float* W     = (const float*)d_in[7];
  const float* memb  = (const float*)d_in[8];
  float* out = (float*)d_out;

  char* ws = (char*)d_ws;
  size_t off = 0;
  unsigned short* xmb   = (unsigned short*)(ws + off); off += (size_t)BT * DD * 2;  // 4 MB
  unsigned short* Wtb   = (unsigned short*)(ws + off); off += (size_t)NN * DD * 2;  // 4 MB
  unsigned short* embT  = (unsigned short*)(ws + off); off += (size_t)NN * EE * 2;  // 256 KB
  unsigned short* projb = (unsigned short*)(ws + off); off += (size_t)BT * EE * 2;  // 256 KB
  float* sqe            = (float*)(ws + off);          off += (size_t)NN * 4;       // 32 KB
  unsigned long long* keys = (unsigned long long*)(ws + off); off += (size_t)BT * 8;// 64 KB
  float* sumexp         = (float*)(ws + off);          off += (size_t)BT * 4;       // 32 KB
  float* ltar           = (float*)(ws + off);          off += (size_t)BT * 4;       // 32 KB

  k_pre   <<<800, 256, 0, stream>>>(xs, mm, memb, gamma, beta, P, W, emb,
                                    xmb, projb, Wtb, embT, sqe, keys, sumexp);
  k_argmin<<<dim3(BT / 64, NS4), 256, 0, stream>>>(projb, embT, sqe, keys);
  k_ce5   <<<dim3(64, 64), 512, 0, stream>>>(xmb, Wtb, keys, sumexp, ltar);
  k_final <<<1, 1024, 0, stream>>>(sumexp, ltar, padm, mm, out);
}

// Round 11
// 196.168 us; speedup vs baseline: 1.0596x; 1.0596x over previous
//
#include <hip/hip_runtime.h>
#include <hip/hip_bf16.h>
#include <math.h>

#define BT   8192   // B*T
#define DD   256    // D
#define EE   16     // E
#define NN   8192   // N codebook entries (C == 1)

typedef __attribute__((ext_vector_type(8))) short short8;   // bf16x8 MFMA frag
typedef __attribute__((ext_vector_type(4))) float f32x4;    // MFMA accumulator

__device__ __forceinline__ unsigned short f2bf(float x) {
  union { float f; unsigned int u; } c; c.f = x;
  unsigned int r = (c.u + 0x7FFFu + ((c.u >> 16) & 1u)) >> 16;   // RNE
  return (unsigned short)r;
}
__device__ __forceinline__ unsigned int ordf(float d) {
  union { float f; unsigned int u; } c; c.f = d;
  return ((int)c.u < 0) ? ~c.u : (c.u | 0x80000000u);
}
__device__ __forceinline__ unsigned long long shflxor64(unsigned long long v, int m) {
  unsigned int lo = (unsigned int)v, hi = (unsigned int)(v >> 32);
  lo = __shfl_xor((int)lo, m);
  hi = __shfl_xor((int)hi, m);
  return ((unsigned long long)hi << 32) | lo;
}
__device__ __forceinline__ void gload_lds16(const void* g, void* l) {
  __builtin_amdgcn_global_load_lds((const __attribute__((address_space(1))) void*)g,
                                   (__attribute__((address_space(3))) void*)l, 16, 0, 0);
}

// ---------------- k_pre: fused Wt-transpose + embT + LN/proj/xmb ------------
// blocks [0,512):    W[d][n] fp32 -> Wt[n][d] bf16 (LDS-tiled, coalesced writes)
// blocks [512,544):  emb -> embT bf16 + sqe(half) + keys init (+done=0 @512)
// blocks [544,800):  xmb bf16 cast, LayerNorm, projb bf16, sumexp zero
// v7-kept: LN/proj section stages P/gamma/beta in LDS.
#define XT_LD 65   // float4 row stride (64 + 1 pad -> conflict-free)
__global__ __launch_bounds__(256) void k_pre(const float* __restrict__ xs,
                                             const int* __restrict__ mm,
                                             const float* __restrict__ memb,
                                             const float* __restrict__ gamma,
                                             const float* __restrict__ beta,
                                             const float* __restrict__ P,
                                             const float* __restrict__ W,
                                             const float* __restrict__ emb,
                                             unsigned short* __restrict__ xmb,
                                             unsigned short* __restrict__ projb,
                                             unsigned short* __restrict__ Wt,
                                             unsigned short* __restrict__ embT,
                                             float* __restrict__ sqe,
                                             unsigned long long* __restrict__ keys,
                                             float* __restrict__ sumexp,
                                             int* __restrict__ done) {
  __shared__ __align__(16) float xt[32 * XT_LD * 4];   // 33 KB shared scratch
  __shared__ float stats[32][2];
  __shared__ __align__(16) float Pl[DD * EE];          // 16 KB (LN blocks)
  __shared__ __align__(16) float gl[DD], bl[DD];       //  2 KB
  int bid = blockIdx.x;
  int tid = threadIdx.x;

  if (bid < 512) {             // ---- Wt transpose: 64n x 64d tile ----
    int n0 = (bid & 127) * 64;
    int d0 = (bid >> 7) * 64;
    #pragma unroll
    for (int pass = 0; pass < 16; pass++) {
      int idx = pass * 256 + tid;
      int dd = idx >> 6, ln = idx & 63;
      xt[ln * 65 + dd] = W[(size_t)(d0 + dd) * NN + n0 + ln];
    }
    __syncthreads();
    #pragma unroll
    for (int pass = 0; pass < 2; pass++) {
      int g = pass * 256 + tid;
      int row = g >> 3, c8 = g & 7;
      short8 v;
      #pragma unroll
      for (int i = 0; i < 8; i++) v[i] = (short)f2bf(xt[row * 65 + c8 * 8 + i]);
      *(short8*)(Wt + (size_t)(n0 + row) * DD + d0 + c8 * 8) = v;
    }
    return;
  }
  if (bid < 544) {             // ---- embT + sqe(half) + keys ----
    if (bid == 512 && tid == 0)
      __hip_atomic_store(done, 0, __ATOMIC_RELAXED, __HIP_MEMORY_SCOPE_AGENT);
    int n = (bid - 512) * 256 + tid;
    float e[EE];
    float sq = 0.f;
    #pragma unroll
    for (int k = 0; k < EE; k++) { e[k] = emb[k * NN + n]; sq += e[k] * e[k]; }
    short8 lo, hi;
    #pragma unroll
    for (int k = 0; k < 8; k++) { lo[k] = (short)f2bf(e[k]); hi[k] = (short)f2bf(e[k + 8]); }
    *(short8*)(embT + (size_t)n * EE)     = lo;
    *(short8*)(embT + (size_t)n * EE + 8) = hi;
    sqe[n] = 0.5f * sq;        // pre-halved: argmin(0.5|e|^2 - p.e) == argmin dist
    keys[n] = ~0ULL;
    return;
  }
  // ---- LN + projection + xmb ----
  int pb = bid - 544;
  int t0 = pb * 32;
  int w = tid >> 6;
  int col4 = tid & 63;
  float4 mb4 = ((const float4*)memb)[col4];

  // stage P/gamma/beta to LDS (completes by the first __syncthreads)
  #pragma unroll
  for (int i = tid; i < DD * EE / 4; i += 256)
    ((float4*)Pl)[i] = ((const float4*)P)[i];
  if (tid < DD / 4) {
    ((float4*)gl)[tid] = ((const float4*)gamma)[tid];
    ((float4*)bl)[tid] = ((const float4*)beta)[tid];
  }

  #pragma unroll
  for (int j = 0; j < 8; j++) {
    int k = tid + j * 256;
    int row = w + j * 4;
    float4 xv = ((const float4*)xs)[(size_t)pb * 2048 + k];
    int m = mm[t0 + row];
    float4 v = m ? mb4 : xv;
    ushort2 o01 = { f2bf(v.x), f2bf(v.y) };
    ushort2 o23 = { f2bf(v.z), f2bf(v.w) };
    ((ushort2*)(xmb + (size_t)(t0 + row) * DD + col4 * 4))[0] = o01;
    ((ushort2*)(xmb + (size_t)(t0 + row) * DD + col4 * 4))[1] = o23;
    *(float4*)&xt[(row * XT_LD + col4) * 4] = xv;
  }
  __syncthreads();
  {
    int t = tid >> 3, g = tid & 7;
    float s = 0.f, s2 = 0.f;
    #pragma unroll
    for (int i = 0; i < 8; i++) {
      float4 v = *(const float4*)&xt[(t * XT_LD + g * 8 + i) * 4];
      s  += v.x + v.y + v.z + v.w;
      s2 += v.x * v.x + v.y * v.y + v.z * v.z + v.w * v.w;
    }
    #pragma unroll
    for (int m = 1; m <= 4; m <<= 1) { s += __shfl_xor(s, m); s2 += __shfl_xor(s2, m); }
    if (g == 0) {
      float mu = s * (1.0f / DD);
      float var = s2 * (1.0f / DD) - mu * mu;
      stats[t][0] = mu;
      stats[t][1] = rsqrtf(var + 1e-5f);
    }
  }
  if (tid < 32) sumexp[t0 + tid] = 0.f;
  __syncthreads();
  {
    int t = tid >> 3, e0 = (tid & 7) * 2;
    float mu = stats[t][0], rstd = stats[t][1];
    float a0 = 0.f, a1 = 0.f;
    for (int d = 0; d < DD; d += 4) {
      float4 xv = *(const float4*)&xt[(t * XT_LD + (d >> 2)) * 4];
      float xd[4] = { xv.x, xv.y, xv.z, xv.w };
      #pragma unroll
      for (int dd = 0; dd < 4; dd++) {
        float h = (xd[dd] - mu) * rstd * gl[d + dd] + bl[d + dd];
        a0 += h * Pl[(d + dd) * EE + e0];
        a1 += h * Pl[(d + dd) * EE + e0 + 1];
      }
    }
    ushort2 o = { f2bf(a0), f2bf(a1) };
    *(ushort2*)(projb + (size_t)(t0 + t) * EE + e0) = o;
  }
}

// ------- k_argmin: MFMA dist + 32-bit (ord,idx) argmin ----------------------
// v7-kept: sqe pre-halved; 32-bit best-ord/best-idx in the hot loop; first-
// occurrence tie semantics preserved.
#define NS4 8
#define ASEG (NN / NS4)   // 1024 n per block
__global__ __launch_bounds__(256) void k_argmin(const unsigned short* __restrict__ projb,
                                                const unsigned short* __restrict__ embT,
                                                const float* __restrict__ sqe,
                                                unsigned long long* __restrict__ keys) {
  int tid = threadIdx.x;
  int w = tid >> 6, lane = tid & 63;
  int q = lane >> 4, c = lane & 15;
  int tw = blockIdx.x * 64 + w * 16;
  int nseg = blockIdx.y * ASEG;

  short8 a = {0, 0, 0, 0, 0, 0, 0, 0};
  if (q < 2) a = *(const short8*)(projb + (size_t)(tw + c) * EE + q * 8);

  unsigned int bo[4], bi[4];
  #pragma unroll
  for (int r = 0; r < 4; r++) { bo[r] = 0xFFFFFFFFu; bi[r] = 0u; }

  #pragma unroll 2
  for (int it = 0; it < ASEG / 16; it++) {
    int n = nseg + it * 16 + c;
    short8 b = {0, 0, 0, 0, 0, 0, 0, 0};
    if (q < 2) b = *(const short8*)(embT + (size_t)n * EE + q * 8);
    float sqh = sqe[n];
    f32x4 acc = (f32x4){0.f, 0.f, 0.f, 0.f};
    acc = __builtin_amdgcn_mfma_f32_16x16x32_bf16(a, b, acc, 0, 0, 0);
    #pragma unroll
    for (int r = 0; r < 4; r++) {
      float dist = sqh - acc[r];
      unsigned int u = ordf(dist);
      if (u < bo[r]) { bo[r] = u; bi[r] = (unsigned int)n; }
    }
  }
  unsigned long long bk[4];
  #pragma unroll
  for (int r = 0; r < 4; r++)
    bk[r] = ((unsigned long long)bo[r] << 32) | bi[r];
  #pragma unroll
  for (int r = 0; r < 4; r++) {
    #pragma unroll
    for (int m = 1; m <= 8; m <<= 1) {
      unsigned long long o = shflxor64(bk[r], m);
      bk[r] = o < bk[r] ? o : bk[r];
    }
  }
  if (c == 0) {
    #pragma unroll
    for (int r = 0; r < 4; r++)
      atomicMin(&keys[tw + q * 4 + r], bk[r]);
  }
}

// ------- k_ce5: 128x128-tile MFMA GEMM + FENCE-FREE fused finisher ----------
// GEMM = v5 EXACT (proven best: 56.4-56.9us; v6/v9/v10 retiles all regressed
// -> this structure is the measured ceiling short of a full 8-phase port).
// Finisher v2 (round-7 lesson applied): NO __threadfence() (its buffer_wbl2
// x4096 blocks serialized the XCD L2s, 10x regress). Instead, cross-XCD
// visibility comes from DEVICE-SCOPE ATOMICS only: sumexp's atomicAdd is
// already agent-scope; ltar's target-store becomes a relaxed agent-scope
// atomic store (coherent cache bits on the store, no writeback instruction).
// Each wave's vmem ops drain at the __syncthreads (implicit vmcnt(0)) BEFORE
// tid0's counter RMW issues -> data is at the coherence point before the
// counter increments. Last block reads with agent-scope loads. Saves the
// k_final dispatch (~15us per the r7-vs-r8 aux delta: 98.4 vs 113.6us).
__global__ __launch_bounds__(512, 4) void k_ce5(const unsigned short* __restrict__ xmb,
                                                const unsigned short* __restrict__ Wt,
                                                const unsigned long long* __restrict__ keys,
                                                float* __restrict__ sumexp,
                                                float* __restrict__ ltar,
                                                const int* __restrict__ padm,
                                                const int* __restrict__ mm,
                                                int* __restrict__ done,
                                                float* __restrict__ out) {
  __shared__ __align__(16) unsigned short ldsA[3][128 * 32];   // 3 x 8 KB
  __shared__ __align__(16) unsigned short ldsB[3][128 * 32];   // 3 x 8 KB
  int tid = threadIdx.x;
  int lane = tid & 63;
  int w = tid >> 6;
  int q = lane >> 4, c = lane & 15;
  int wm = w >> 1, wn = w & 1;
  int t0 = blockIdx.x * 128;
  int n0 = blockIdx.y * 128;
  int sw = q ^ ((c >> 1) & 3);      // swizzled K-quarter for fragment reads

  f32x4 acc[2][4];
  #pragma unroll
  for (int mi = 0; mi < 2; mi++)
    #pragma unroll
    for (int ni = 0; ni < 4; ni++) acc[mi][ni] = (f32x4){0.f, 0.f, 0.f, 0.f};

  #define STAGE(buf, itv) do {                                                  \
    int kk_ = (itv) * 32;                                                       \
    int g = tid;                                                                \
    int row = g >> 2;                                                           \
    int qg = (g & 3) ^ ((g >> 3) & 3);                                          \
    gload_lds16(xmb + (size_t)(t0 + row) * DD + kk_ + qg * 8,                   \
                ldsA[buf] + g * 8);                                             \
    gload_lds16(Wt + (size_t)(n0 + row) * DD + kk_ + qg * 8,                    \
                ldsB[buf] + g * 8);                                             \
  } while (0)

  // prologue: 2 stages in flight; wait only stage 0 (vmcnt(2) = stage 1 open)
  STAGE(0, 0);
  STAGE(1, 1);
  asm volatile("s_waitcnt vmcnt(2)" ::: "memory");
  __builtin_amdgcn_s_barrier();

  #pragma unroll
  for (int it = 0; it < 8; it++) {
    const int cur = it % 3;
    const int nxt = (it + 2) % 3;
    if (it + 2 < 8) {                       // issue stage it+2 (2 loads)
      if (nxt == 0)      STAGE(0, it + 2);
      else if (nxt == 1) STAGE(1, it + 2);
      else               STAGE(2, it + 2);
    }

    short8 a[2], b[4];
    #pragma unroll
    for (int mi = 0; mi < 2; mi++)
      a[mi] = *(const short8*)(ldsA[cur] + (wm * 32 + mi * 16 + c) * 32 + sw * 8);
    #pragma unroll
    for (int ni = 0; ni < 4; ni++)
      b[ni] = *(const short8*)(ldsB[cur] + (wn * 64 + ni * 16 + c) * 32 + sw * 8);
    #pragma unroll
    for (int mi = 0; mi < 2; mi++)
      #pragma unroll
      for (int ni = 0; ni < 4; ni++)
        acc[mi][ni] = __builtin_amdgcn_mfma_f32_16x16x32_bf16(a[mi], b[ni], acc[mi][ni], 0, 0, 0);

    // counted-vmcnt barrier: stage(it+1) guaranteed landed, stage(it+2)
    // stays in flight across the barrier. Never drain to 0 in steady state.
    if (it < 6) {
      asm volatile("s_waitcnt vmcnt(2)" ::: "memory");
      __builtin_amdgcn_s_barrier();
    } else if (it == 6) {
      asm volatile("s_waitcnt vmcnt(0)" ::: "memory");
      __builtin_amdgcn_s_barrier();
    }
  }
  #undef STAGE

  // epilogue: exp-sum per row + target-logit capture (unique writer grid-wide)
  int tg[2][4];
  #pragma unroll
  for (int mi = 0; mi < 2; mi++)
    #pragma unroll
    for (int r = 0; r < 4; r++)
      tg[mi][r] = (int)(unsigned int)(keys[t0 + wm * 32 + mi * 16 + q * 4 + r] & 0xFFFFFFFFULL);

  float rs[2][4];
  #pragma unroll
  for (int mi = 0; mi < 2; mi++)
    #pragma unroll
    for (int r = 0; r < 4; r++) rs[mi][r] = 0.f;

  #pragma unroll
  for (int mi = 0; mi < 2; mi++)
    #pragma unroll
    for (int ni = 0; ni < 4; ni++) {
      int col = n0 + wn * 64 + ni * 16 + c;
      #pragma unroll
      for (int r = 0; r < 4; r++) {
        float v = acc[mi][ni][r];
        if (col == tg[mi][r])
          __hip_atomic_store(&ltar[t0 + wm * 32 + mi * 16 + q * 4 + r], v,
                             __ATOMIC_RELAXED, __HIP_MEMORY_SCOPE_AGENT);
        rs[mi][r] += __expf(v);
      }
    }

  #pragma unroll
  for (int mi = 0; mi < 2; mi++)
    #pragma unroll
    for (int r = 0; r < 4; r++) {
      float s = rs[mi][r];
      s += __shfl_xor(s, 1);
      s += __shfl_xor(s, 2);
      s += __shfl_xor(s, 4);
      s += __shfl_xor(s, 8);
      if (c == 0)
        atomicAdd(&sumexp[t0 + wm * 32 + mi * 16 + q * 4 + r], s);
    }

  // ---- fence-free fused finisher ----
  __syncthreads();   // per-wave vmcnt(0) drain: data atomics reach coherence
  __shared__ int lastFlag;
  if (tid == 0) {
    int prev = __hip_atomic_fetch_add(done, 1, __ATOMIC_RELAXED,
                                      __HIP_MEMORY_SCOPE_AGENT);
    lastFlag = (prev == 64 * 64 - 1);
  }
  __syncthreads();
  if (!lastFlag) return;

  float fsum = 0.f, fcnt = 0.f;
  for (int t = tid; t < BT; t += 512) {
    float se = __hip_atomic_load(&sumexp[t], __ATOMIC_RELAXED, __HIP_MEMORY_SCOPE_AGENT);
    float lt = __hip_atomic_load(&ltar[t], __ATOMIC_RELAXED, __HIP_MEMORY_SCOPE_AGENT);
    float ce = __logf(se) - lt;
    if (padm[t] && mm[t]) { fsum += ce; fcnt += 1.f; }
  }
  #pragma unroll
  for (int off = 32; off; off >>= 1) {
    fsum += __shfl_down(fsum, off);
    fcnt += __shfl_down(fcnt, off);
  }
  __shared__ float frs[8], frc[8];
  if (lane == 0) { frs[w] = fsum; frc[w] = fcnt; }
  __syncthreads();
  if (tid == 0) {
    float S = 0.f, Cn = 0.f;
    #pragma unroll
    for (int i = 0; i < 8; i++) { S += frs[i]; Cn += frc[i]; }
    out[0] = S / Cn;
  }
}

extern "C" void kernel_launch(void* const* d_in, const int* in_sizes, int n_in,
                              void* d_out, int out_size, void* d_ws, size_t ws_size,
                              hipStream_t stream) {
  const float* xs    = (const float*)d_in[0];
  const int*   padm  = (const int*)d_in[1];
  const int*   mm    = (const int*)d_in[2];
  const float* gamma = (const float*)d_in[3];
  const float* beta  = (const float*)d_in[4];
  const float* P     = (const float*)d_in[5];
  const float* emb   = (const float*)d_in[6];
  const float* W     = (const float*)d_in[7];
  const float* memb  = (const float*)d_in[8];
  float* out = (float*)d_out;

  char* ws = (char*)d_ws;
  size_t off = 0;
  unsigned short* xmb   = (unsigned short*)(ws + off); off += (size_t)BT * DD * 2;  // 4 MB
  unsigned short* Wtb   = (unsigned short*)(ws + off); off += (size_t)NN * DD * 2;  // 4 MB
  unsigned short* embT  = (unsigned short*)(ws + off); off += (size_t)NN * EE * 2;  // 256 KB
  unsigned short* projb = (unsigned short*)(ws + off); off += (size_t)BT * EE * 2;  // 256 KB
  float* sqe            = (float*)(ws + off);          off += (size_t)NN * 4;       // 32 KB
  unsigned long long* keys = (unsigned long long*)(ws + off); off += (size_t)BT * 8;// 64 KB
  float* sumexp         = (float*)(ws + off);          off += (size_t)BT * 4;       // 32 KB
  float* ltar           = (float*)(ws + off);          off += (size_t)BT * 4;       // 32 KB
  int* done             = (int*)(ws + off);            off += 64;

  k_pre   <<<800, 256, 0, stream>>>(xs, mm, memb, gamma, beta, P, W, emb,
                                    xmb, projb, Wtb, embT, sqe, keys, sumexp, done);
  k_argmin<<<dim3(BT / 64, NS4), 256, 0, stream>>>(projb, embT, sqe, keys);
  k_ce5   <<<dim3(64, 64), 512, 0, stream>>>(xmb, Wtb, keys, sumexp, ltar,
                                             padm, mm, done, out);
}

// Round 12
// 169.700 us; speedup vs baseline: 1.2248x; 1.1560x over previous
//
#include <hip/hip_runtime.h>
#include <hip/hip_bf16.h>
#include <math.h>

#define BT   8192   // B*T
#define DD   256    // D
#define EE   16     // E
#define NN   8192   // N codebook entries (C == 1)

typedef __attribute__((ext_vector_type(8))) short short8;   // bf16x8 MFMA frag
typedef __attribute__((ext_vector_type(4))) float f32x4;    // MFMA accumulator

__device__ __forceinline__ unsigned short f2bf(float x) {
  union { float f; unsigned int u; } c; c.f = x;
  unsigned int r = (c.u + 0x7FFFu + ((c.u >> 16) & 1u)) >> 16;   // RNE
  return (unsigned short)r;
}
__device__ __forceinline__ unsigned int ordf(float d) {
  union { float f; unsigned int u; } c; c.f = d;
  return ((int)c.u < 0) ? ~c.u : (c.u | 0x80000000u);
}
__device__ __forceinline__ unsigned long long shflxor64(unsigned long long v, int m) {
  unsigned int lo = (unsigned int)v, hi = (unsigned int)(v >> 32);
  lo = __shfl_xor((int)lo, m);
  hi = __shfl_xor((int)hi, m);
  return ((unsigned long long)hi << 32) | lo;
}
__device__ __forceinline__ void gload_lds16(const void* g, void* l) {
  __builtin_amdgcn_global_load_lds((const __attribute__((address_space(1))) void*)g,
                                   (__attribute__((address_space(3))) void*)l, 16, 0, 0);
}

// ---------------- k_pre: fused Wt-transpose + embT + LN/proj/xmb ------------
// blocks [0,512):    W[d][n] fp32 -> Wt[n][d] bf16 (LDS-tiled, coalesced writes)
// blocks [512,544):  emb -> embT bf16 + sqe(half) + keys init
// blocks [544,800):  xmb bf16 cast, LayerNorm, projb bf16, sumexp zero
// v7-kept: LN/proj stages P/gamma/beta in LDS. v12: transpose GLOBAL loads
// vectorized float4 along n (16 dword -> 4 dwordx4 per thread); LDS scatter
// writes stay 2-way-bank (65*4B row stride, 65 === 1 mod 32) = free; the
// read/bf16-store path is byte-identical to r8.
#define XT_LD 65   // float4 row stride (64 + 1 pad -> conflict-free)
__global__ __launch_bounds__(256) void k_pre(const float* __restrict__ xs,
                                             const int* __restrict__ mm,
                                             const float* __restrict__ memb,
                                             const float* __restrict__ gamma,
                                             const float* __restrict__ beta,
                                             const float* __restrict__ P,
                                             const float* __restrict__ W,
                                             const float* __restrict__ emb,
                                             unsigned short* __restrict__ xmb,
                                             unsigned short* __restrict__ projb,
                                             unsigned short* __restrict__ Wt,
                                             unsigned short* __restrict__ embT,
                                             float* __restrict__ sqe,
                                             unsigned long long* __restrict__ keys,
                                             float* __restrict__ sumexp) {
  __shared__ __align__(16) float xt[32 * XT_LD * 4];   // 33 KB shared scratch
  __shared__ float stats[32][2];
  __shared__ __align__(16) float Pl[DD * EE];          // 16 KB (LN blocks)
  __shared__ __align__(16) float gl[DD], bl[DD];       //  2 KB
  int bid = blockIdx.x;
  int tid = threadIdx.x;

  if (bid < 512) {             // ---- Wt transpose: 64n x 64d tile ----
    int n0 = (bid & 127) * 64;
    int d0 = (bid >> 7) * 64;
    // load: 16 lanes cover one d-row's 64 n as 4 x float4 (256B coalesced);
    // LDS scatter (ln*65 + dd) is 2-way-bank (free)
    #pragma unroll
    for (int pass = 0; pass < 4; pass++) {
      int s = pass * 256 + tid;            // 1024 float4 slots
      int dd = s >> 4, ln4 = (s & 15) * 4;
      float4 v4 = *(const float4*)&W[(size_t)(d0 + dd) * NN + n0 + ln4];
      xt[(ln4 + 0) * 65 + dd] = v4.x;
      xt[(ln4 + 1) * 65 + dd] = v4.y;
      xt[(ln4 + 2) * 65 + dd] = v4.z;
      xt[(ln4 + 3) * 65 + dd] = v4.w;
    }
    __syncthreads();
    // store: thread g -> row n=g>>3, 8 d-elems; 8 lanes cover 128B line
    #pragma unroll
    for (int pass = 0; pass < 2; pass++) {
      int g = pass * 256 + tid;
      int row = g >> 3, c8 = g & 7;
      short8 v;
      #pragma unroll
      for (int i = 0; i < 8; i++) v[i] = (short)f2bf(xt[row * 65 + c8 * 8 + i]);
      *(short8*)(Wt + (size_t)(n0 + row) * DD + d0 + c8 * 8) = v;
    }
    return;
  }
  if (bid < 544) {             // ---- embT + sqe(half) + keys ----
    int n = (bid - 512) * 256 + tid;
    float e[EE];
    float sq = 0.f;
    #pragma unroll
    for (int k = 0; k < EE; k++) { e[k] = emb[k * NN + n]; sq += e[k] * e[k]; }
    short8 lo, hi;
    #pragma unroll
    for (int k = 0; k < 8; k++) { lo[k] = (short)f2bf(e[k]); hi[k] = (short)f2bf(e[k + 8]); }
    *(short8*)(embT + (size_t)n * EE)     = lo;
    *(short8*)(embT + (size_t)n * EE + 8) = hi;
    sqe[n] = 0.5f * sq;        // pre-halved: argmin(0.5|e|^2 - p.e) == argmin dist
    keys[n] = ~0ULL;
    return;
  }
  // ---- LN + projection + xmb ----
  int pb = bid - 544;
  int t0 = pb * 32;
  int w = tid >> 6;
  int col4 = tid & 63;
  float4 mb4 = ((const float4*)memb)[col4];

  // stage P/gamma/beta to LDS (completes by the first __syncthreads)
  #pragma unroll
  for (int i = tid; i < DD * EE / 4; i += 256)
    ((float4*)Pl)[i] = ((const float4*)P)[i];
  if (tid < DD / 4) {
    ((float4*)gl)[tid] = ((const float4*)gamma)[tid];
    ((float4*)bl)[tid] = ((const float4*)beta)[tid];
  }

  #pragma unroll
  for (int j = 0; j < 8; j++) {
    int k = tid + j * 256;
    int row = w + j * 4;
    float4 xv = ((const float4*)xs)[(size_t)pb * 2048 + k];
    int m = mm[t0 + row];
    float4 v = m ? mb4 : xv;
    ushort2 o01 = { f2bf(v.x), f2bf(v.y) };
    ushort2 o23 = { f2bf(v.z), f2bf(v.w) };
    ((ushort2*)(xmb + (size_t)(t0 + row) * DD + col4 * 4))[0] = o01;
    ((ushort2*)(xmb + (size_t)(t0 + row) * DD + col4 * 4))[1] = o23;
    *(float4*)&xt[(row * XT_LD + col4) * 4] = xv;
  }
  __syncthreads();
  {
    int t = tid >> 3, g = tid & 7;
    float s = 0.f, s2 = 0.f;
    #pragma unroll
    for (int i = 0; i < 8; i++) {
      float4 v = *(const float4*)&xt[(t * XT_LD + g * 8 + i) * 4];
      s  += v.x + v.y + v.z + v.w;
      s2 += v.x * v.x + v.y * v.y + v.z * v.z + v.w * v.w;
    }
    #pragma unroll
    for (int m = 1; m <= 4; m <<= 1) { s += __shfl_xor(s, m); s2 += __shfl_xor(s2, m); }
    if (g == 0) {
      float mu = s * (1.0f / DD);
      float var = s2 * (1.0f / DD) - mu * mu;
      stats[t][0] = mu;
      stats[t][1] = rsqrtf(var + 1e-5f);
    }
  }
  if (tid < 32) sumexp[t0 + tid] = 0.f;
  __syncthreads();
  {
    int t = tid >> 3, e0 = (tid & 7) * 2;
    float mu = stats[t][0], rstd = stats[t][1];
    float a0 = 0.f, a1 = 0.f;
    for (int d = 0; d < DD; d += 4) {
      float4 xv = *(const float4*)&xt[(t * XT_LD + (d >> 2)) * 4];
      float xd[4] = { xv.x, xv.y, xv.z, xv.w };
      #pragma unroll
      for (int dd = 0; dd < 4; dd++) {
        float h = (xd[dd] - mu) * rstd * gl[d + dd] + bl[d + dd];
        a0 += h * Pl[(d + dd) * EE + e0];
        a1 += h * Pl[(d + dd) * EE + e0 + 1];
      }
    }
    ushort2 o = { f2bf(a0), f2bf(a1) };
    *(ushort2*)(projb + (size_t)(t0 + t) * EE + e0) = o;
  }
}

// ------- k_argmin: MFMA dist + 32-bit (ord,idx) argmin ----------------------
// v7-kept: sqe pre-halved; 32-bit best-ord/best-idx in the hot loop; first-
// occurrence tie semantics preserved.
#define NS4 8
#define ASEG (NN / NS4)   // 1024 n per block
__global__ __launch_bounds__(256) void k_argmin(const unsigned short* __restrict__ projb,
                                                const unsigned short* __restrict__ embT,
                                                const float* __restrict__ sqe,
                                                unsigned long long* __restrict__ keys) {
  int tid = threadIdx.x;
  int w = tid >> 6, lane = tid & 63;
  int q = lane >> 4, c = lane & 15;
  int tw = blockIdx.x * 64 + w * 16;
  int nseg = blockIdx.y * ASEG;

  short8 a = {0, 0, 0, 0, 0, 0, 0, 0};
  if (q < 2) a = *(const short8*)(projb + (size_t)(tw + c) * EE + q * 8);

  unsigned int bo[4], bi[4];
  #pragma unroll
  for (int r = 0; r < 4; r++) { bo[r] = 0xFFFFFFFFu; bi[r] = 0u; }

  #pragma unroll 2
  for (int it = 0; it < ASEG / 16; it++) {
    int n = nseg + it * 16 + c;
    short8 b = {0, 0, 0, 0, 0, 0, 0, 0};
    if (q < 2) b = *(const short8*)(embT + (size_t)n * EE + q * 8);
    float sqh = sqe[n];
    f32x4 acc = (f32x4){0.f, 0.f, 0.f, 0.f};
    acc = __builtin_amdgcn_mfma_f32_16x16x32_bf16(a, b, acc, 0, 0, 0);
    #pragma unroll
    for (int r = 0; r < 4; r++) {
      float dist = sqh - acc[r];
      unsigned int u = ordf(dist);
      if (u < bo[r]) { bo[r] = u; bi[r] = (unsigned int)n; }
    }
  }
  unsigned long long bk[4];
  #pragma unroll
  for (int r = 0; r < 4; r++)
    bk[r] = ((unsigned long long)bo[r] << 32) | bi[r];
  #pragma unroll
  for (int r = 0; r < 4; r++) {
    #pragma unroll
    for (int m = 1; m <= 8; m <<= 1) {
      unsigned long long o = shflxor64(bk[r], m);
      bk[r] = o < bk[r] ? o : bk[r];
    }
  }
  if (c == 0) {
    #pragma unroll
    for (int r = 0; r < 4; r++)
      atomicMin(&keys[tw + q * 4 + r], bk[r]);
  }
}

// ------- k_ce5: 128x128-tile MFMA GEMM, XOR-swizzled LDS, fused epilogue ----
// FINAL = v5/r8 EXACT (best measured: 56.4-56.9us). Session evidence that
// this is the structural ceiling: (1) retiles v6 (64x64/wave @512thr), v9
// (256^2 big-tile), v10 (single-stage full-K) all regressed — register
// pressure, 1-block/CU exposure, or 512B-row bank conflicts; (2) schedule
// variants (dbuf v2, counted-vmcnt v5) moved 61->57 only — m233's ~72%
// 2-phase stage+sync overhead is structural; (3) epilogue fusion variants
// (r7 threadfence, r11 atomic-protocol) cost 485/34us inside the kernel vs
// the ~8-16us a dispatch removal saves. Structure: 512 thr = 8 waves of
// 32x64, 72 combined regs, 4 waves/SIMD, 2 blocks/CU; 3 LDS buffers, stage
// 2 ahead, counted vmcnt(2) at each raw s_barrier (stage it+2 stays in
// flight; never drain to 0 in steady state).
__global__ __launch_bounds__(512, 4) void k_ce5(const unsigned short* __restrict__ xmb,
                                                const unsigned short* __restrict__ Wt,
                                                const unsigned long long* __restrict__ keys,
                                                float* __restrict__ sumexp,
                                                float* __restrict__ ltar) {
  __shared__ __align__(16) unsigned short ldsA[3][128 * 32];   // 3 x 8 KB
  __shared__ __align__(16) unsigned short ldsB[3][128 * 32];   // 3 x 8 KB
  int tid = threadIdx.x;
  int lane = tid & 63;
  int w = tid >> 6;
  int q = lane >> 4, c = lane & 15;
  int wm = w >> 1, wn = w & 1;
  int t0 = blockIdx.x * 128;
  int n0 = blockIdx.y * 128;
  int sw = q ^ ((c >> 1) & 3);      // swizzled K-quarter for fragment reads

  f32x4 acc[2][4];
  #pragma unroll
  for (int mi = 0; mi < 2; mi++)
    #pragma unroll
    for (int ni = 0; ni < 4; ni++) acc[mi][ni] = (f32x4){0.f, 0.f, 0.f, 0.f};

  #define STAGE(buf, itv) do {                                                  \
    int kk_ = (itv) * 32;                                                       \
    int g = tid;                                                                \
    int row = g >> 2;                                                           \
    int qg = (g & 3) ^ ((g >> 3) & 3);                                          \
    gload_lds16(xmb + (size_t)(t0 + row) * DD + kk_ + qg * 8,                   \
                ldsA[buf] + g * 8);                                             \
    gload_lds16(Wt + (size_t)(n0 + row) * DD + kk_ + qg * 8,                    \
                ldsB[buf] + g * 8);                                             \
  } while (0)

  // prologue: 2 stages in flight; wait only stage 0 (vmcnt(2) = stage 1 open)
  STAGE(0, 0);
  STAGE(1, 1);
  asm volatile("s_waitcnt vmcnt(2)" ::: "memory");
  __builtin_amdgcn_s_barrier();

  #pragma unroll
  for (int it = 0; it < 8; it++) {
    const int cur = it % 3;
    const int nxt = (it + 2) % 3;
    if (it + 2 < 8) {                       // issue stage it+2 (2 loads)
      if (nxt == 0)      STAGE(0, it + 2);
      else if (nxt == 1) STAGE(1, it + 2);
      else               STAGE(2, it + 2);
    }

    short8 a[2], b[4];
    #pragma unroll
    for (int mi = 0; mi < 2; mi++)
      a[mi] = *(const short8*)(ldsA[cur] + (wm * 32 + mi * 16 + c) * 32 + sw * 8);
    #pragma unroll
    for (int ni = 0; ni < 4; ni++)
      b[ni] = *(const short8*)(ldsB[cur] + (wn * 64 + ni * 16 + c) * 32 + sw * 8);
    #pragma unroll
    for (int mi = 0; mi < 2; mi++)
      #pragma unroll
      for (int ni = 0; ni < 4; ni++)
        acc[mi][ni] = __builtin_amdgcn_mfma_f32_16x16x32_bf16(a[mi], b[ni], acc[mi][ni], 0, 0, 0);

    // counted-vmcnt barrier: stage(it+1) guaranteed landed, stage(it+2)
    // stays in flight across the barrier. Never drain to 0 in steady state.
    if (it < 6) {
      asm volatile("s_waitcnt vmcnt(2)" ::: "memory");
      __builtin_amdgcn_s_barrier();
    } else if (it == 6) {
      asm volatile("s_waitcnt vmcnt(0)" ::: "memory");
      __builtin_amdgcn_s_barrier();
    }
  }
  #undef STAGE

  // epilogue: exp-sum per row + target-logit capture (unique writer grid-wide)
  int tg[2][4];
  #pragma unroll
  for (int mi = 0; mi < 2; mi++)
    #pragma unroll
    for (int r = 0; r < 4; r++)
      tg[mi][r] = (int)(unsigned int)(keys[t0 + wm * 32 + mi * 16 + q * 4 + r] & 0xFFFFFFFFULL);

  float rs[2][4];
  #pragma unroll
  for (int mi = 0; mi < 2; mi++)
    #pragma unroll
    for (int r = 0; r < 4; r++) rs[mi][r] = 0.f;

  #pragma unroll
  for (int mi = 0; mi < 2; mi++)
    #pragma unroll
    for (int ni = 0; ni < 4; ni++) {
      int col = n0 + wn * 64 + ni * 16 + c;
      #pragma unroll
      for (int r = 0; r < 4; r++) {
        float v = acc[mi][ni][r];
        if (col == tg[mi][r])
          ltar[t0 + wm * 32 + mi * 16 + q * 4 + r] = v;
        rs[mi][r] += __expf(v);
      }
    }

  #pragma unroll
  for (int mi = 0; mi < 2; mi++)
    #pragma unroll
    for (int r = 0; r < 4; r++) {
      float s = rs[mi][r];
      s += __shfl_xor(s, 1);
      s += __shfl_xor(s, 2);
      s += __shfl_xor(s, 4);
      s += __shfl_xor(s, 8);
      if (c == 0)
        atomicAdd(&sumexp[t0 + wm * 32 + mi * 16 + q * 4 + r], s);
    }
}

// ------- final: CE, masked mean ---------------------------------------------
__global__ __launch_bounds__(1024) void k_final(const float* __restrict__ sumexp,
                                                const float* __restrict__ ltar,
                                                const int* __restrict__ padm,
                                                const int* __restrict__ mm,
                                                float* __restrict__ out) {
  int tid = threadIdx.x;
  float sum = 0.f, cnt = 0.f;
  for (int t = tid; t < BT; t += 1024) {
    float ce = __logf(sumexp[t]) - ltar[t];
    if (padm[t] && mm[t]) { sum += ce; cnt += 1.f; }
  }
  #pragma unroll
  for (int off = 32; off; off >>= 1) { sum += __shfl_down(sum, off); cnt += __shfl_down(cnt, off); }
  __shared__ float rs[16], rc[16];
  int wid = tid >> 6, lane = tid & 63;
  if (lane == 0) { rs[wid] = sum; rc[wid] = cnt; }
  __syncthreads();
  if (tid == 0) {
    float S = 0.f, Cn = 0.f;
    for (int i = 0; i < 16; i++) { S += rs[i]; Cn += rc[i]; }
    out[0] = S / Cn;
  }
}

extern "C" void kernel_launch(void* const* d_in, const int* in_sizes, int n_in,
                              void* d_out, int out_size, void* d_ws, size_t ws_size,
                              hipStream_t stream) {
  const float* xs    = (const float*)d_in[0];
  const int*   padm  = (const int*)d_in[1];
  const int*   mm    = (const int*)d_in[2];
  const float* gamma = (const float*)d_in[3];
  const float* beta  = (const float*)d_in[4];
  const float* P     = (const float*)d_in[5];
  const float* emb   = (const float*)d_in[6];
  const float* W     = (const float*)d_in[7];
  const float* memb  = (const float*)d_in[8];
  float* out = (float*)d_out;

  char* ws = (char*)d_ws;
  size_t off = 0;
  unsigned short* xmb   = (unsigned short*)(ws + off); off += (size_t)BT * DD * 2;  // 4 MB
  unsigned short* Wtb   = (unsigned short*)(ws + off); off += (size_t)NN * DD * 2;  // 4 MB
  unsigned short* embT  = (unsigned short*)(ws + off); off += (size_t)NN * EE * 2;  // 256 KB
  unsigned short* projb = (unsigned short*)(ws + off); off += (size_t)BT * EE * 2;  // 256 KB
  float* sqe            = (float*)(ws + off);          off += (size_t)NN * 4;       // 32 KB
  unsigned long long* keys = (unsigned long long*)(ws + off); off += (size_t)BT * 8;// 64 KB
  float* sumexp         = (float*)(ws + off);          off += (size_t)BT * 4;       // 32 KB
  float* ltar           = (float*)(ws + off);          off += (size_t)BT * 4;       // 32 KB

  k_pre   <<<800, 256, 0, stream>>>(xs, mm, memb, gamma, beta, P, W, emb,
                                    xmb, projb, Wtb, embT, sqe, keys, sumexp);
  k_argmin<<<dim3(BT / 64, NS4), 256, 0, stream>>>(projb, embT, sqe, keys);
  k_ce5   <<<dim3(64, 64), 512, 0, stream>>>(xmb, Wtb, keys, sumexp, ltar);
  k_final <<<1, 1024, 0, stream>>>(sumexp, ltar, padm, mm, out);
}